// Round 16
// baseline (96.672 us; speedup 1.0000x reference)
//
#include <hip/hip_runtime.h>

// DetectPostProcess: softmax -> decode -> per-(b,c) top-200 -> greedy NMS.
// Decisions (ordering, top-K membership, IoU>0.5) identical to rounds 2..15
// (f64 everywhere it matters; f32 IoU fast path guarded by exact f64
// recompute within |margin|<=1e-5).
// Round 16: select2 at 1024 threads/block. Per-thread key work halves
// (2 uint4 = 32 u8 keys), and residency becomes 2 blocks x 16 waves =
// 32/32 waves/CU (was 2.5 blocks x 8 waves = 20/32). Block-rounds 2.5 -> 1.25.
// Pivot/collect/sort/IoU/scan phases unchanged in semantics.
// Outputs: objs [B,NC,K,5] then keep [B,NC,K] (as 0.0/1.0), flat in d_out.

constexpr int B = 32;
constexpr int A = 32768;     // power of two
constexpr int ABITS = 15;    // log2(A)
constexpr int NCP1 = 21;
constexpr int NC = 20;
constexpr int K = 200;
constexpr int NBIN = 256;    // 8-bit bins; bin 0 = below threshold
#define KBASE 0x3D4Cu        // bits(0.05f) >> 16; min nonzero 16-bit key

#define TH_CONF 0.05
#define TH_IOU  0.5

// ============================ FAST PATH =====================================
// prep_fast: per (b,a): m (f32 max), S (f64 sum), and 20 transposed u8 bins.
__global__ __launch_bounds__(256) void prep_fast(
    const float* __restrict__ conf, float* __restrict__ marr,
    double* __restrict__ sarr, unsigned char* __restrict__ keys) {
  int idx = blockIdx.x * 256 + threadIdx.x;   // 0 .. B*A-1
  int b = idx >> ABITS;
  int a = idx & (A - 1);
  const float* cp = conf + (size_t)idx * NCP1;
  float x[NCP1];
#pragma unroll
  for (int i = 0; i < NCP1; ++i) x[i] = cp[i];
  float m = x[0];
#pragma unroll
  for (int i = 1; i < NCP1; ++i) m = fmaxf(m, x[i]);
  double e[NCP1];
  double S = 0.0;
#pragma unroll
  for (int i = 0; i < NCP1; ++i) {
    e[i] = exp((double)x[i] - (double)m);
    S += e[i];
  }
  marr[idx] = m;
  sarr[idx] = S;
  double rs = 1.0 / S;
  size_t kbase = ((size_t)(b * NC) << ABITS) + a;
#pragma unroll
  for (int c = 0; c < NC; ++c) {
    double sd = e[c + 1] * rs;                 // ~1ulp from e/S; key-grade only
    unsigned kb = 0;
    if (sd >= TH_CONF) {
      unsigned k16 = __float_as_uint((float)sd) >> 16;   // >= KBASE guaranteed
      kb = min(((k16 - KBASE) >> 1) + 1u, 255u);
    }
    keys[kbase + ((size_t)c << ABITS)] = (unsigned char)kb;
  }
}

// f64 box decode for one anchor.
__device__ __forceinline__ void decode_d(const float* __restrict__ loc,
                                         const float* __restrict__ anchor,
                                         size_t ba, int a, double* o) {
  const float* lp = loc + ba * 4;
  const float* ap = anchor + (size_t)a * 4;
  double l0 = lp[0], l1 = lp[1], l2 = lp[2], l3 = lp[3];
  double cx = ap[0], cy = ap[1], aw = ap[2], ah = ap[3];
  double X = (l0 * 0.125) * aw + cx;
  double Y = (l1 * 0.125) * ah + cy;
  double bw = exp(l2 * 0.125) * aw;
  double bh = exp(l3 * 0.125) * ah;
  o[0] = X - bw * 0.5;
  o[1] = Y - bh * 0.5;
  o[2] = X + bw * 0.5;
  o[3] = Y + bh * 0.5;
}

// select2: one block per (b,c), 1024 threads. Fused selection + NMS, u8 keys.
__global__ __launch_bounds__(1024) void select2_kernel(
    const float* __restrict__ conf, const float* __restrict__ marr,
    const double* __restrict__ sarr, const float* __restrict__ loc,
    const float* __restrict__ anchor, const unsigned char* __restrict__ keys,
    float* __restrict__ out) {
  constexpr int NT = 1024;
  __shared__ unsigned hist[NBIN];
  __shared__ unsigned wtot[16], wsuf[16];
  __shared__ unsigned long long cand[512];
  __shared__ int clist[512];
  __shared__ float4 cf4[K];             // f32 box (fast path)
  __shared__ float car[K];              // f32 area
  __shared__ double4 cd4[K];            // f64 box (guard path)
  __shared__ double dar[K];             // f64 area
  __shared__ unsigned cols[K * 8];      // column-major IoU bits: cols[j*8+w5]
  __shared__ unsigned kpw[8];           // keep bit words
  __shared__ unsigned sh_cnt, sh_selbin, sh_total;

  int tid = threadIdx.x;
  unsigned lane = tid & 63, wid = tid >> 6;

  // XCD-bijective swizzle: all 20 classes of image b on one XCD
  int B_ = blockIdx.x;
  int x8 = B_ & 7;
  int r8 = B_ >> 3;                      // 0..79
  int b = x8 + 8 * (r8 / NC);            // 0..31
  int c = r8 % NC;
  int bc = b * NC + c;
  size_t base = (size_t)b << ABITS;
  const uint4* kv = (const uint4*)(keys + ((size_t)bc << ABITS));  // 16 keys ea

  if (tid == 0) sh_cnt = 0;

  // ---- 1. single key pass: 2 uint4 (32 u8 keys) into registers + hist ----
  if (tid < NBIN) hist[tid] = 0;
  __syncthreads();
  uint4 kreg[2];
#pragma unroll
  for (int it = 0; it < 2; ++it) {
    int i = tid + it * NT;               // < A/16 = 2048
    uint4 v = kv[i];
    kreg[it] = v;
    unsigned w[4] = {v.x, v.y, v.z, v.w};
#pragma unroll
    for (int q = 0; q < 4; ++q) {
#pragma unroll
      for (int by = 0; by < 4; ++by) {
        unsigned kb = (w[q] >> (by * 8)) & 0xFFu;
        if (kb) atomicAdd(&hist[kb], 1u);
      }
    }
  }
  __syncthreads();

  // ---- 2. shfl suffix scan (cnt_ge) + exact 8-bit pivot ----
  unsigned h0 = 0, h1 = 0;
  if (tid < NBIN / 2) { h0 = hist[2 * tid]; h1 = hist[2 * tid + 1]; }
  unsigned s = h0 + h1;
  unsigned S = s;
#pragma unroll
  for (int d = 1; d < 64; d <<= 1) {
    unsigned o = __shfl_down(S, d, 64);
    if (lane + d < 64) S += o;
  }
  if (lane == 0) wtot[wid] = S;
  __syncthreads();
  if (tid < 16) {
    unsigned acc = 0;
    for (int w2 = tid + 1; w2 < 16; ++w2) acc += wtot[w2];
    wsuf[tid] = acc;
    if (tid == 0) sh_total = acc + wtot[0];
  }
  __syncthreads();
  unsigned Sfull = S + wsuf[wid];
  unsigned above2 = Sfull - s;
  unsigned cg1 = h1 + above2;
  unsigned cg0 = h0 + cg1;
  // bin 0 never selected; pivot = max bin >= 1 with cnt_ge >= K
  if (cg1 >= (unsigned)K && above2 < (unsigned)K) sh_selbin = tid * 2 + 1;
  if (tid > 0 && tid < NBIN / 2 && cg0 >= (unsigned)K && cg1 < (unsigned)K)
    sh_selbin = tid * 2;
  __syncthreads();
  unsigned pivot8 = (sh_total - hist[0] <= (unsigned)K) ? 1u : sh_selbin;

  // ---- 3. collect candidates FROM REGISTERS (superset of top-K) ----
#pragma unroll
  for (int it = 0; it < 2; ++it) {
    int i = tid + it * NT;
    uint4 v = kreg[it];
    unsigned w[4] = {v.x, v.y, v.z, v.w};
#pragma unroll
    for (int q = 0; q < 4; ++q) {
#pragma unroll
      for (int by = 0; by < 4; ++by) {
        unsigned kb = (w[q] >> (by * 8)) & 0xFFu;
        if (kb >= pivot8) {
          unsigned pos = atomicAdd(&sh_cnt, 1u);
          if (pos < 512) clist[pos] = i * 16 + q * 4 + by;
        }
      }
    }
  }
  __syncthreads();
  unsigned ccount = sh_cnt < 512u ? sh_cnt : 512u;
  unsigned Ct = ccount < (unsigned)K ? ccount : (unsigned)K;

  // ---- 4. exact f64 scores for candidates; build sort keys ----
  if (tid < 512) {
    unsigned long long key = 0ull;
    if ((unsigned)tid < ccount) {
      int a = clist[tid];
      size_t ba = base + a;
      double sd = exp((double)conf[ba * NCP1 + (c + 1)] - (double)marr[ba]) / sarr[ba];
      if (sd >= TH_CONF) {
        unsigned long long db = (unsigned long long)__double_as_longlong(sd);
        key = (db & 0xFFFFFFFFFFFF0000ull) |
              (unsigned long long)(65535u - (unsigned)tid * 0u) ;
        key = (db & 0xFFFFFFFFFFFF0000ull) |
              (unsigned long long)(65535u - (unsigned)a);
      }
    }
    cand[tid] = key;
  }
  __syncthreads();

  // ---- 5. bitonic sort desc (shfl for j<64): (score bits desc, idx asc) ----
  unsigned n2 = (ccount <= 256u) ? 256u : 512u;
  unsigned long long v = ((unsigned)tid < n2) ? cand[tid] : 0ull;
  for (unsigned k2 = 2; k2 <= n2; k2 <<= 1) {
    for (unsigned j = k2 >> 1; j > 0; j >>= 1) {
      unsigned long long p;
      if (j >= 64) {
        __syncthreads();
        if ((unsigned)tid < n2) cand[tid] = v;
        __syncthreads();
        p = ((unsigned)tid < n2) ? cand[tid ^ j] : 0ull;
      } else {
        p = __shfl_xor(v, (int)j, 64);
      }
      if ((unsigned)tid < n2) {
        bool desc = ((tid & (int)k2) == 0);
        bool lower = ((tid & (int)j) == 0);
        bool takemax = (lower == desc);
        bool vge = (v >= p);
        v = takemax ? (vge ? v : p) : (vge ? p : v);
      }
    }
  }
  __syncthreads();
  if ((unsigned)tid < n2) cand[tid] = v;
  __syncthreads();

  // ---- 6. decode candidate boxes (f64) + packed f32/f64 mirrors ----
  if ((unsigned)tid < Ct) {
    unsigned long long key = cand[tid];
    bool valid = (key >> 16) != 0ull;
    double o[4] = {0.0, 0.0, 0.0, 0.0};
    double aa = 0.0;
    if (valid) {
      unsigned a = (65535u - (unsigned)(key & 0xFFFFull)) & (A - 1);
      decode_d(loc, anchor, base + a, a, o);
      aa = (o[2] - o[0]) * (o[3] - o[1]);
    }
    cd4[tid] = make_double4(o[0], o[1], o[2], o[3]);
    dar[tid] = aa;
    cf4[tid] = make_float4((float)o[0], (float)o[1], (float)o[2], (float)o[3]);
    car[tid] = (float)aa;
  }
  __syncthreads();

  // ---- 7. IoU COLUMN words (upper triangle i<j only);
  //         f32 fast path, exact f64 guard when |margin| <= 1e-5 ----
  int Cti = (int)Ct;
  int total_jw = Cti * 7;
  for (int id = tid; id < total_jw; id += NT) {
    int j = id % Cti;
    int w5 = id / Cti;                  // 0..6
    int ilo = w5 * 32;
    unsigned bits = 0;
    if (ilo < j) {
      int ihi = (ilo + 32 < j) ? (ilo + 32) : j;
      float4 bj = cf4[j];
      float aj = car[j];
      for (int i = ilo; i < ihi; ++i) {
        float4 bi = cf4[i];
        float ltx = fmaxf(bi.x, bj.x);
        float lty = fmaxf(bi.y, bj.y);
        float rbx = fminf(bi.z, bj.z);
        float rby = fminf(bi.w, bj.w);
        float iw = fmaxf(rbx - ltx, 0.f);
        float ih = fmaxf(rby - lty, 0.f);
        float inter = iw * ih;
        float den = car[i] + aj - inter + 1e-9f;
        float dmar = inter - 0.5f * den;
        bool bit;
        if (fabsf(dmar) > 1e-5f) {
          bit = dmar > 0.f;
        } else {
          double4 Bi = cd4[i], Bj = cd4[j];
          double LTX = fmax(Bi.x, Bj.x);
          double LTY = fmax(Bi.y, Bj.y);
          double RBX = fmin(Bi.z, Bj.z);
          double RBY = fmin(Bi.w, Bj.w);
          double IW = fmax(RBX - LTX, 0.0);
          double IH = fmax(RBY - LTY, 0.0);
          double INTER = IW * IH;
          double DEN = dar[i] + dar[j] - INTER + 1e-9;
          bit = INTER > 0.5 * DEN;
        }
        if (bit) bits |= 1u << (i - ilo);
      }
    }
    cols[j * 8 + w5] = bits;
  }
  __syncthreads();

  // ---- 8. register-resident greedy scan (wave 0; matches lax.scan) ----
  if (tid < 64) {
    unsigned cb[4][7];                  // [slot][w5]; column j = slot*64 + tid
#pragma unroll
    for (int s2 = 0; s2 < 4; ++s2) {
      int j = s2 * 64 + tid;
#pragma unroll
      for (int w5 = 0; w5 < 7; ++w5)
        cb[s2][w5] = (j < Cti) ? cols[j * 8 + w5] : 0u;
    }
    unsigned sup[4] = {0u, 0u, 0u, 0u}; // suppressed flag per owned column
    unsigned kw[7] = {0u, 0u, 0u, 0u, 0u, 0u, 0u};
#pragma unroll
    for (int w5 = 0; w5 < 7; ++w5) {
      const int slot = w5 >> 1;
#pragma unroll
      for (int ii = 0; ii < 32; ++ii) {
        int i = w5 * 32 + ii;
        if (i < Cti) {
          int lane2 = (w5 & 1) * 32 + ii;           // = i & 63 (uniform)
          unsigned sflag = (unsigned)__builtin_amdgcn_readlane(
              (int)sup[slot], lane2);
          unsigned km = (sflag == 0u) ? 0xFFFFFFFFu : 0u;
          kw[w5] |= (km & 1u) << ii;
#pragma unroll
          for (int s2 = 0; s2 < 4; ++s2)
            sup[s2] |= ((cb[s2][w5] >> ii) & 1u) & km;
        }
      }
    }
    if (tid == 0) {
#pragma unroll
      for (int w5 = 0; w5 < 7; ++w5) kpw[w5] = kw[w5];
      kpw[7] = 0u;
    }
  }
  __syncthreads();

  // ---- 9. write objs + keep ----
  if (tid < K) {
    bool kkeep = ((unsigned)tid < Ct) &&
                 (((kpw[tid >> 5] >> (tid & 31)) & 1u) != 0u) &&
                 ((cand[tid] >> 16) != 0ull);
    float o0 = 0.f, o1v = 0.f, o2v = 0.f, o3v = 0.f, o4 = 0.f;
    if (kkeep) {
      double4 Bi = cd4[tid];
      o0 = (float)Bi.x; o1v = (float)Bi.y; o2v = (float)Bi.z; o3v = (float)Bi.w;
      double sd = __longlong_as_double(
          (long long)(cand[tid] & 0xFFFFFFFFFFFF0000ull));
      o4 = (float)sd;
    }
    size_t ob = ((size_t)bc * K + tid) * 5;
    out[ob + 0] = o0; out[ob + 1] = o1v; out[ob + 2] = o2v;
    out[ob + 3] = o3v; out[ob + 4] = o4;
    out[(size_t)B * NC * K * 5 + (size_t)bc * K + tid] = kkeep ? 1.f : 0.f;
  }
}

// ============================ FALLBACK PATH (round-2, passing) ==============
__global__ __launch_bounds__(256) void prep_kernel(
    const float* __restrict__ conf, float* __restrict__ marr,
    double* __restrict__ sarr) {
  int idx = blockIdx.x * 256 + threadIdx.x;
  const float* cp = conf + (size_t)idx * NCP1;
  float x[NCP1];
#pragma unroll
  for (int i = 0; i < NCP1; ++i) x[i] = cp[i];
  float m = x[0];
#pragma unroll
  for (int i = 1; i < NCP1; ++i) m = fmaxf(m, x[i]);
  double S = 0.0;
#pragma unroll
  for (int i = 0; i < NCP1; ++i) S += exp((double)x[i] - (double)m);
  marr[idx] = m;
  sarr[idx] = S;
}

__device__ __forceinline__ double get_sd(const float* __restrict__ conf,
                                         const float* __restrict__ marr,
                                         const double* __restrict__ sarr,
                                         size_t ba, int c) {
  const float* cp = conf + ba * NCP1;
  float m;
  double S;
  if (sarr) {
    m = marr[ba];
    S = sarr[ba];
  } else {
    m = cp[0];
    for (int i = 1; i < NCP1; ++i) m = fmaxf(m, cp[i]);
    S = 0.0;
    for (int i = 0; i < NCP1; ++i) S += exp((double)cp[i] - (double)m);
  }
  return exp((double)cp[c + 1] - (double)m) / S;
}

__global__ __launch_bounds__(256) void select_nms_kernel(
    const float* __restrict__ conf, const float* __restrict__ marr,
    const double* __restrict__ sarr, const float* __restrict__ loc,
    const float* __restrict__ anchor, float* __restrict__ out) {
  __shared__ __align__(16) unsigned short s16[A];
  __shared__ unsigned hist[256];
  __shared__ unsigned scan0[256];
  __shared__ unsigned long long cand[512];
  __shared__ unsigned sh_cnt, sh_selbin, sh_need, sh_ctot;

  double* cbd = (double*)s16;
  double* ar = cbd + K * 4;
  unsigned* rows = (unsigned*)(ar + K);
  unsigned* kp = rows + K * 8;

  int tid = threadIdx.x;
  int bc = blockIdx.x;
  int b = bc / NC, c = bc % NC;
  size_t base = (size_t)b << ABITS;

  for (int a = tid; a < A; a += 256) {
    double sd = get_sd(conf, marr, sarr, base + a, c);
    unsigned short key = 0;
    if (sd >= TH_CONF) {
      float f = (float)sd;
      key = (unsigned short)(__float_as_uint(f) >> 16);
    }
    s16[a] = key;
  }
  __syncthreads();

  unsigned need = K, pfx = 0;
  bool smallcase = false;
  for (int p = 0; p < 2; ++p) {
    hist[tid] = 0;
    __syncthreads();
    for (int a = tid; a < A; a += 256) {
      unsigned v = s16[a];
      if (v && (p == 0 || (v >> 8) == pfx))
        atomicAdd(&hist[(p == 0) ? (v >> 8) : (v & 0xFFu)], 1u);
    }
    __syncthreads();
    scan0[tid] = hist[tid];
    __syncthreads();
    for (int st = 1; st < 256; st <<= 1) {
      unsigned mine = scan0[tid];
      unsigned oth = (tid + st < 256) ? scan0[tid + st] : 0u;
      __syncthreads();
      scan0[tid] = mine + oth;
      __syncthreads();
    }
    if (p == 0) {
      if (tid == 0) sh_ctot = scan0[0];
      __syncthreads();
      if (sh_ctot <= (unsigned)K) { smallcase = true; break; }
    }
    unsigned nxt = (tid == 255) ? 0u : scan0[tid + 1];
    if (scan0[tid] >= need && nxt < need) { sh_selbin = tid; sh_need = need - nxt; }
    __syncthreads();
    pfx = (pfx << 8) | sh_selbin;
    need = sh_need;
    __syncthreads();
  }
  unsigned pivot16 = smallcase ? 0x3D4Cu : pfx;

  if (tid == 0) sh_cnt = 0;
  __syncthreads();
  for (int a = tid; a < A; a += 256) {
    double sd = get_sd(conf, marr, sarr, base + a, c);
    if (sd >= TH_CONF) {
      float f = (float)sd;
      if ((__float_as_uint(f) >> 16) >= pivot16) {
        unsigned pos = atomicAdd(&sh_cnt, 1u);
        if (pos < 512) {
          unsigned long long db = (unsigned long long)__double_as_longlong(sd);
          cand[pos] = (db & 0xFFFFFFFFFFFF0000ull) |
                      (unsigned long long)(65535u - (unsigned)a);
        }
      }
    }
  }
  __syncthreads();
  unsigned ccount = sh_cnt < 512u ? sh_cnt : 512u;
  unsigned Ct = ccount < (unsigned)K ? ccount : (unsigned)K;
  for (int i = tid; i < 512; i += 256)
    if ((unsigned)i >= ccount) cand[i] = 0ull;
  __syncthreads();

  for (unsigned k2 = 2; k2 <= 512; k2 <<= 1) {
    for (unsigned j = k2 >> 1; j > 0; j >>= 1) {
      for (unsigned i = tid; i < 512; i += 256) {
        unsigned ixj = i ^ j;
        if (ixj > i) {
          unsigned long long va = cand[i], vb = cand[ixj];
          bool desc = ((i & k2) == 0);
          if (desc ? (va < vb) : (va > vb)) { cand[i] = vb; cand[ixj] = va; }
        }
      }
      __syncthreads();
    }
  }

  if ((unsigned)tid < Ct) {
    unsigned a = 65535u - (unsigned)(cand[tid] & 0xFFFFull);
    double o[4];
    decode_d(loc, anchor, base + a, a, o);
    cbd[tid * 4 + 0] = o[0]; cbd[tid * 4 + 1] = o[1];
    cbd[tid * 4 + 2] = o[2]; cbd[tid * 4 + 3] = o[3];
    ar[tid] = (o[2] - o[0]) * (o[3] - o[1]);
  }
  __syncthreads();

  for (int id = tid; id < (int)Ct * 8; id += 256) {
    int i = id >> 3, w = id & 7;
    double xi0 = cbd[i * 4 + 0], yi0 = cbd[i * 4 + 1];
    double xi1 = cbd[i * 4 + 2], yi1 = cbd[i * 4 + 3];
    double ai = ar[i];
    unsigned bits = 0;
    int j0 = w * 32;
    for (int jj = 0; jj < 32; ++jj) {
      int j = j0 + jj;
      if (j < (int)Ct) {
        double ltx = fmax(xi0, cbd[j * 4 + 0]);
        double lty = fmax(yi0, cbd[j * 4 + 1]);
        double rbx = fmin(xi1, cbd[j * 4 + 2]);
        double rby = fmin(yi1, cbd[j * 4 + 3]);
        double iw = fmax(rbx - ltx, 0.0);
        double ih = fmax(rby - lty, 0.0);
        double inter = iw * ih;
        double iou = inter / (ai + ar[j] - inter + 1e-9);
        if (iou > TH_IOU) bits |= (1u << jj);
      }
    }
    rows[i * 8 + w] = bits;
  }
  __syncthreads();

  if (tid < 64) {
    unsigned supp = 0;
    for (int i = 0; i < (int)Ct; ++i) {
      unsigned wsrc = __shfl(supp, i >> 5);
      bool kkeep = ((wsrc >> (i & 31)) & 1u) == 0u;
      if (tid == 0) kp[i] = kkeep ? 1u : 0u;
      unsigned rw = (tid < 8) ? rows[i * 8 + tid] : 0u;
      if (kkeep) supp |= rw;
    }
  }
  __syncthreads();

  if (tid < K) {
    bool kkeep = ((unsigned)tid < Ct) && (kp[tid] != 0u);
    float o0 = 0.f, o1 = 0.f, o2 = 0.f, o3 = 0.f, o4 = 0.f;
    if (kkeep) {
      o0 = (float)cbd[tid * 4 + 0]; o1 = (float)cbd[tid * 4 + 1];
      o2 = (float)cbd[tid * 4 + 2]; o3 = (float)cbd[tid * 4 + 3];
      double sd = __longlong_as_double(
          (long long)(cand[tid] & 0xFFFFFFFFFFFF0000ull));
      o4 = (float)sd;
    }
    size_t ob = ((size_t)bc * K + tid) * 5;
    out[ob + 0] = o0; out[ob + 1] = o1; out[ob + 2] = o2;
    out[ob + 3] = o3; out[ob + 4] = o4;
    out[(size_t)B * NC * K * 5 + (size_t)bc * K + tid] = kkeep ? 1.f : 0.f;
  }
}

extern "C" void kernel_launch(void* const* d_in, const int* in_sizes, int n_in,
                              void* d_out, int out_size, void* d_ws, size_t ws_size,
                              hipStream_t stream) {
  (void)in_sizes; (void)n_in; (void)out_size;
  const float* conf = (const float*)d_in[0];
  const float* loc = (const float*)d_in[1];
  const float* anchor = (const float*)d_in[2];
  float* out = (float*)d_out;

  size_t nBA = (size_t)B * A;
  size_t off_sarr = 0;
  size_t off_marr = off_sarr + nBA * sizeof(double);
  size_t off_keys = off_marr + nBA * sizeof(float);
  size_t need_fast = off_keys + nBA * NC * sizeof(unsigned char);  // ~32.5 MB
  size_t need_mid = nBA * (sizeof(float) + sizeof(double));        // 12 MB

  if (ws_size >= need_fast) {
    double* sarr = (double*)((char*)d_ws + off_sarr);
    float* marr = (float*)((char*)d_ws + off_marr);
    unsigned char* keys = (unsigned char*)((char*)d_ws + off_keys);
    prep_fast<<<(B * A) / 256, 256, 0, stream>>>(conf, marr, sarr, keys);
    select2_kernel<<<B * NC, 1024, 0, stream>>>(conf, marr, sarr, loc, anchor,
                                                keys, out);
  } else if (ws_size >= need_mid) {
    float* marr = (float*)d_ws;
    double* sarr = (double*)((char*)d_ws + nBA * sizeof(float));
    prep_kernel<<<(B * A) / 256, 256, 0, stream>>>(conf, marr, sarr);
    select_nms_kernel<<<B * NC, 256, 0, stream>>>(conf, marr, sarr, loc, anchor, out);
  } else {
    select_nms_kernel<<<B * NC, 256, 0, stream>>>(conf, nullptr, nullptr, loc, anchor, out);
  }
}

// Round 17
// 78.813 us; speedup vs baseline: 1.2266x; 1.2266x over previous
//
#include <hip/hip_runtime.h>

// DetectPostProcess: softmax -> decode -> per-(b,c) top-200 -> greedy NMS.
// Decisions (ordering, top-K membership, IoU>0.5) identical to rounds 2..15
// (f64 everywhere it matters; f32 IoU fast path guarded by exact f64
// recompute within |margin|<=1e-5).
// Round 17: revert to the round-15 configuration (512-thread select2) —
// measured optimum (79.3us). Round 16's 1024-thread variant regressed:
// tail phases engage <=512 threads, so 16-wave barriers + idle waves
// lengthened the per-block critical path.
// Outputs: objs [B,NC,K,5] then keep [B,NC,K] (as 0.0/1.0), flat in d_out.

constexpr int B = 32;
constexpr int A = 32768;     // power of two
constexpr int ABITS = 15;    // log2(A)
constexpr int NCP1 = 21;
constexpr int NC = 20;
constexpr int K = 200;
constexpr int NBIN = 256;    // 8-bit bins; bin 0 = below threshold
#define KBASE 0x3D4Cu        // bits(0.05f) >> 16; min nonzero 16-bit key

#define TH_CONF 0.05
#define TH_IOU  0.5

// ============================ FAST PATH =====================================
// prep_fast: per (b,a): m (f32 max), S (f64 sum), and 20 transposed u8 bins.
__global__ __launch_bounds__(256) void prep_fast(
    const float* __restrict__ conf, float* __restrict__ marr,
    double* __restrict__ sarr, unsigned char* __restrict__ keys) {
  int idx = blockIdx.x * 256 + threadIdx.x;   // 0 .. B*A-1
  int b = idx >> ABITS;
  int a = idx & (A - 1);
  const float* cp = conf + (size_t)idx * NCP1;
  float x[NCP1];
#pragma unroll
  for (int i = 0; i < NCP1; ++i) x[i] = cp[i];
  float m = x[0];
#pragma unroll
  for (int i = 1; i < NCP1; ++i) m = fmaxf(m, x[i]);
  double e[NCP1];
  double S = 0.0;
#pragma unroll
  for (int i = 0; i < NCP1; ++i) {
    e[i] = exp((double)x[i] - (double)m);
    S += e[i];
  }
  marr[idx] = m;
  sarr[idx] = S;
  double rs = 1.0 / S;
  size_t kbase = ((size_t)(b * NC) << ABITS) + a;
#pragma unroll
  for (int c = 0; c < NC; ++c) {
    double sd = e[c + 1] * rs;                 // ~1ulp from e/S; key-grade only
    unsigned kb = 0;
    if (sd >= TH_CONF) {
      unsigned k16 = __float_as_uint((float)sd) >> 16;   // >= KBASE guaranteed
      kb = min(((k16 - KBASE) >> 1) + 1u, 255u);
    }
    keys[kbase + ((size_t)c << ABITS)] = (unsigned char)kb;
  }
}

// f64 box decode for one anchor.
__device__ __forceinline__ void decode_d(const float* __restrict__ loc,
                                         const float* __restrict__ anchor,
                                         size_t ba, int a, double* o) {
  const float* lp = loc + ba * 4;
  const float* ap = anchor + (size_t)a * 4;
  double l0 = lp[0], l1 = lp[1], l2 = lp[2], l3 = lp[3];
  double cx = ap[0], cy = ap[1], aw = ap[2], ah = ap[3];
  double X = (l0 * 0.125) * aw + cx;
  double Y = (l1 * 0.125) * ah + cy;
  double bw = exp(l2 * 0.125) * aw;
  double bh = exp(l3 * 0.125) * ah;
  o[0] = X - bw * 0.5;
  o[1] = Y - bh * 0.5;
  o[2] = X + bw * 0.5;
  o[3] = Y + bh * 0.5;
}

// select2: one block per (b,c). Full fused selection + NMS, u8 keys.
__global__ __launch_bounds__(512) void select2_kernel(
    const float* __restrict__ conf, const float* __restrict__ marr,
    const double* __restrict__ sarr, const float* __restrict__ loc,
    const float* __restrict__ anchor, const unsigned char* __restrict__ keys,
    float* __restrict__ out) {
  constexpr int NT = 512;
  __shared__ unsigned hist[NBIN];
  __shared__ unsigned wtot[8], wsuf[8];
  __shared__ unsigned long long cand[512];
  __shared__ int clist[512];
  __shared__ float4 cf4[K];             // f32 box (fast path)
  __shared__ float car[K];              // f32 area
  __shared__ double4 cd4[K];            // f64 box (guard path)
  __shared__ double dar[K];             // f64 area
  __shared__ unsigned cols[K * 8];      // column-major IoU bits: cols[j*8+w5]
  __shared__ unsigned kpw[8];           // keep bit words
  __shared__ unsigned sh_cnt, sh_selbin, sh_total;

  int tid = threadIdx.x;
  unsigned lane = tid & 63, wid = tid >> 6;

  // XCD-bijective swizzle: all 20 classes of image b on one XCD
  int B_ = blockIdx.x;
  int x8 = B_ & 7;
  int r8 = B_ >> 3;                      // 0..79
  int b = x8 + 8 * (r8 / NC);            // 0..31
  int c = r8 % NC;
  int bc = b * NC + c;
  size_t base = (size_t)b << ABITS;
  const uint4* kv = (const uint4*)(keys + ((size_t)bc << ABITS));  // 16 keys ea

  if (tid == 0) sh_cnt = 0;

  // ---- 1. single key pass: 4 uint4 (64 u8 keys) into registers + hist ----
  for (int i = tid; i < NBIN; i += NT) hist[i] = 0;
  __syncthreads();
  uint4 kreg[4];
#pragma unroll
  for (int it = 0; it < 4; ++it) {
    int i = tid + it * NT;               // < A/16 = 2048
    uint4 v = kv[i];
    kreg[it] = v;
    unsigned w[4] = {v.x, v.y, v.z, v.w};
#pragma unroll
    for (int q = 0; q < 4; ++q) {
#pragma unroll
      for (int by = 0; by < 4; ++by) {
        unsigned kb = (w[q] >> (by * 8)) & 0xFFu;
        if (kb) atomicAdd(&hist[kb], 1u);
      }
    }
  }
  __syncthreads();

  // ---- 2. shfl suffix scan (cnt_ge) + exact 8-bit pivot ----
  unsigned h0 = 0, h1 = 0;
  if (tid < NBIN / 2) { h0 = hist[2 * tid]; h1 = hist[2 * tid + 1]; }
  unsigned s = h0 + h1;
  unsigned S = s;
#pragma unroll
  for (int d = 1; d < 64; d <<= 1) {
    unsigned o = __shfl_down(S, d, 64);
    if (lane + d < 64) S += o;
  }
  if (lane == 0) wtot[wid] = S;
  __syncthreads();
  if (tid < 8) {
    unsigned acc = 0;
    for (int w2 = tid + 1; w2 < 8; ++w2) acc += wtot[w2];
    wsuf[tid] = acc;
    if (tid == 0) sh_total = acc + wtot[0];
  }
  __syncthreads();
  unsigned Sfull = S + wsuf[wid];
  unsigned above2 = Sfull - s;
  unsigned cg1 = h1 + above2;
  unsigned cg0 = h0 + cg1;
  // bin 0 never selected; pivot = max bin >= 1 with cnt_ge >= K
  if (cg1 >= (unsigned)K && above2 < (unsigned)K) sh_selbin = tid * 2 + 1;
  if (tid > 0 && cg0 >= (unsigned)K && cg1 < (unsigned)K) sh_selbin = tid * 2;
  __syncthreads();
  unsigned pivot8 = (sh_total - hist[0] <= (unsigned)K) ? 1u : sh_selbin;

  // ---- 3. collect candidates FROM REGISTERS (superset of top-K) ----
#pragma unroll
  for (int it = 0; it < 4; ++it) {
    int i = tid + it * NT;
    uint4 v = kreg[it];
    unsigned w[4] = {v.x, v.y, v.z, v.w};
#pragma unroll
    for (int q = 0; q < 4; ++q) {
#pragma unroll
      for (int by = 0; by < 4; ++by) {
        unsigned kb = (w[q] >> (by * 8)) & 0xFFu;
        if (kb >= pivot8) {
          unsigned pos = atomicAdd(&sh_cnt, 1u);
          if (pos < 512) clist[pos] = i * 16 + q * 4 + by;
        }
      }
    }
  }
  __syncthreads();
  unsigned ccount = sh_cnt < 512u ? sh_cnt : 512u;
  unsigned Ct = ccount < (unsigned)K ? ccount : (unsigned)K;

  // ---- 4. exact f64 scores for candidates; build sort keys ----
  for (int i = tid; i < 512; i += NT) {
    unsigned long long key = 0ull;
    if ((unsigned)i < ccount) {
      int a = clist[i];
      size_t ba = base + a;
      double sd = exp((double)conf[ba * NCP1 + (c + 1)] - (double)marr[ba]) / sarr[ba];
      if (sd >= TH_CONF) {
        unsigned long long db = (unsigned long long)__double_as_longlong(sd);
        key = (db & 0xFFFFFFFFFFFF0000ull) |
              (unsigned long long)(65535u - (unsigned)a);
      }
    }
    cand[i] = key;
  }
  __syncthreads();

  // ---- 5. bitonic sort desc (shfl for j<64): (score bits desc, idx asc) ----
  unsigned n2 = (ccount <= 256u) ? 256u : 512u;
  unsigned long long v = ((unsigned)tid < n2) ? cand[tid] : 0ull;
  for (unsigned k2 = 2; k2 <= n2; k2 <<= 1) {
    for (unsigned j = k2 >> 1; j > 0; j >>= 1) {
      unsigned long long p;
      if (j >= 64) {
        __syncthreads();
        if ((unsigned)tid < n2) cand[tid] = v;
        __syncthreads();
        p = ((unsigned)tid < n2) ? cand[tid ^ j] : 0ull;
      } else {
        p = __shfl_xor(v, (int)j, 64);
      }
      if ((unsigned)tid < n2) {
        bool desc = ((tid & (int)k2) == 0);
        bool lower = ((tid & (int)j) == 0);
        bool takemax = (lower == desc);
        bool vge = (v >= p);
        v = takemax ? (vge ? v : p) : (vge ? p : v);
      }
    }
  }
  __syncthreads();
  if ((unsigned)tid < n2) cand[tid] = v;
  __syncthreads();

  // ---- 6. decode candidate boxes (f64) + packed f32/f64 mirrors ----
  if ((unsigned)tid < Ct) {
    unsigned long long key = cand[tid];
    bool valid = (key >> 16) != 0ull;
    double o[4] = {0.0, 0.0, 0.0, 0.0};
    double aa = 0.0;
    if (valid) {
      unsigned a = (65535u - (unsigned)(key & 0xFFFFull)) & (A - 1);
      decode_d(loc, anchor, base + a, a, o);
      aa = (o[2] - o[0]) * (o[3] - o[1]);
    }
    cd4[tid] = make_double4(o[0], o[1], o[2], o[3]);
    dar[tid] = aa;
    cf4[tid] = make_float4((float)o[0], (float)o[1], (float)o[2], (float)o[3]);
    car[tid] = (float)aa;
  }
  __syncthreads();

  // ---- 7. IoU COLUMN words (upper triangle i<j only);
  //         f32 fast path, exact f64 guard when |margin| <= 1e-5 ----
  int Cti = (int)Ct;
  int total_jw = Cti * 7;
  for (int id = tid; id < total_jw; id += NT) {
    int j = id % Cti;
    int w5 = id / Cti;                  // 0..6
    int ilo = w5 * 32;
    unsigned bits = 0;
    if (ilo < j) {
      int ihi = (ilo + 32 < j) ? (ilo + 32) : j;
      float4 bj = cf4[j];
      float aj = car[j];
      for (int i = ilo; i < ihi; ++i) {
        float4 bi = cf4[i];
        float ltx = fmaxf(bi.x, bj.x);
        float lty = fmaxf(bi.y, bj.y);
        float rbx = fminf(bi.z, bj.z);
        float rby = fminf(bi.w, bj.w);
        float iw = fmaxf(rbx - ltx, 0.f);
        float ih = fmaxf(rby - lty, 0.f);
        float inter = iw * ih;
        float den = car[i] + aj - inter + 1e-9f;
        float dmar = inter - 0.5f * den;
        bool bit;
        if (fabsf(dmar) > 1e-5f) {
          bit = dmar > 0.f;
        } else {
          double4 Bi = cd4[i], Bj = cd4[j];
          double LTX = fmax(Bi.x, Bj.x);
          double LTY = fmax(Bi.y, Bj.y);
          double RBX = fmin(Bi.z, Bj.z);
          double RBY = fmin(Bi.w, Bj.w);
          double IW = fmax(RBX - LTX, 0.0);
          double IH = fmax(RBY - LTY, 0.0);
          double INTER = IW * IH;
          double DEN = dar[i] + dar[j] - INTER + 1e-9;
          bit = INTER > 0.5 * DEN;
        }
        if (bit) bits |= 1u << (i - ilo);
      }
    }
    cols[j * 8 + w5] = bits;
  }
  __syncthreads();

  // ---- 8. register-resident greedy scan (wave 0; matches lax.scan) ----
  if (tid < 64) {
    unsigned cb[4][7];                  // [slot][w5]; column j = slot*64 + tid
#pragma unroll
    for (int s2 = 0; s2 < 4; ++s2) {
      int j = s2 * 64 + tid;
#pragma unroll
      for (int w5 = 0; w5 < 7; ++w5)
        cb[s2][w5] = (j < Cti) ? cols[j * 8 + w5] : 0u;
    }
    unsigned sup[4] = {0u, 0u, 0u, 0u}; // suppressed flag per owned column
    unsigned kw[7] = {0u, 0u, 0u, 0u, 0u, 0u, 0u};
#pragma unroll
    for (int w5 = 0; w5 < 7; ++w5) {
      const int slot = w5 >> 1;
#pragma unroll
      for (int ii = 0; ii < 32; ++ii) {
        int i = w5 * 32 + ii;
        if (i < Cti) {
          int lane2 = (w5 & 1) * 32 + ii;           // = i & 63 (uniform)
          unsigned sflag = (unsigned)__builtin_amdgcn_readlane(
              (int)sup[slot], lane2);
          unsigned km = (sflag == 0u) ? 0xFFFFFFFFu : 0u;
          kw[w5] |= (km & 1u) << ii;
#pragma unroll
          for (int s2 = 0; s2 < 4; ++s2)
            sup[s2] |= ((cb[s2][w5] >> ii) & 1u) & km;
        }
      }
    }
    if (tid == 0) {
#pragma unroll
      for (int w5 = 0; w5 < 7; ++w5) kpw[w5] = kw[w5];
      kpw[7] = 0u;
    }
  }
  __syncthreads();

  // ---- 9. write objs + keep ----
  if (tid < K) {
    bool kkeep = ((unsigned)tid < Ct) &&
                 (((kpw[tid >> 5] >> (tid & 31)) & 1u) != 0u) &&
                 ((cand[tid] >> 16) != 0ull);
    float o0 = 0.f, o1v = 0.f, o2v = 0.f, o3v = 0.f, o4 = 0.f;
    if (kkeep) {
      double4 Bi = cd4[tid];
      o0 = (float)Bi.x; o1v = (float)Bi.y; o2v = (float)Bi.z; o3v = (float)Bi.w;
      double sd = __longlong_as_double(
          (long long)(cand[tid] & 0xFFFFFFFFFFFF0000ull));
      o4 = (float)sd;
    }
    size_t ob = ((size_t)bc * K + tid) * 5;
    out[ob + 0] = o0; out[ob + 1] = o1v; out[ob + 2] = o2v;
    out[ob + 3] = o3v; out[ob + 4] = o4;
    out[(size_t)B * NC * K * 5 + (size_t)bc * K + tid] = kkeep ? 1.f : 0.f;
  }
}

// ============================ FALLBACK PATH (round-2, passing) ==============
__global__ __launch_bounds__(256) void prep_kernel(
    const float* __restrict__ conf, float* __restrict__ marr,
    double* __restrict__ sarr) {
  int idx = blockIdx.x * 256 + threadIdx.x;
  const float* cp = conf + (size_t)idx * NCP1;
  float x[NCP1];
#pragma unroll
  for (int i = 0; i < NCP1; ++i) x[i] = cp[i];
  float m = x[0];
#pragma unroll
  for (int i = 1; i < NCP1; ++i) m = fmaxf(m, x[i]);
  double S = 0.0;
#pragma unroll
  for (int i = 0; i < NCP1; ++i) S += exp((double)x[i] - (double)m);
  marr[idx] = m;
  sarr[idx] = S;
}

__device__ __forceinline__ double get_sd(const float* __restrict__ conf,
                                         const float* __restrict__ marr,
                                         const double* __restrict__ sarr,
                                         size_t ba, int c) {
  const float* cp = conf + ba * NCP1;
  float m;
  double S;
  if (sarr) {
    m = marr[ba];
    S = sarr[ba];
  } else {
    m = cp[0];
    for (int i = 1; i < NCP1; ++i) m = fmaxf(m, cp[i]);
    S = 0.0;
    for (int i = 0; i < NCP1; ++i) S += exp((double)cp[i] - (double)m);
  }
  return exp((double)cp[c + 1] - (double)m) / S;
}

__global__ __launch_bounds__(256) void select_nms_kernel(
    const float* __restrict__ conf, const float* __restrict__ marr,
    const double* __restrict__ sarr, const float* __restrict__ loc,
    const float* __restrict__ anchor, float* __restrict__ out) {
  __shared__ __align__(16) unsigned short s16[A];
  __shared__ unsigned hist[256];
  __shared__ unsigned scan0[256];
  __shared__ unsigned long long cand[512];
  __shared__ unsigned sh_cnt, sh_selbin, sh_need, sh_ctot;

  double* cbd = (double*)s16;
  double* ar = cbd + K * 4;
  unsigned* rows = (unsigned*)(ar + K);
  unsigned* kp = rows + K * 8;

  int tid = threadIdx.x;
  int bc = blockIdx.x;
  int b = bc / NC, c = bc % NC;
  size_t base = (size_t)b << ABITS;

  for (int a = tid; a < A; a += 256) {
    double sd = get_sd(conf, marr, sarr, base + a, c);
    unsigned short key = 0;
    if (sd >= TH_CONF) {
      float f = (float)sd;
      key = (unsigned short)(__float_as_uint(f) >> 16);
    }
    s16[a] = key;
  }
  __syncthreads();

  unsigned need = K, pfx = 0;
  bool smallcase = false;
  for (int p = 0; p < 2; ++p) {
    hist[tid] = 0;
    __syncthreads();
    for (int a = tid; a < A; a += 256) {
      unsigned v = s16[a];
      if (v && (p == 0 || (v >> 8) == pfx))
        atomicAdd(&hist[(p == 0) ? (v >> 8) : (v & 0xFFu)], 1u);
    }
    __syncthreads();
    scan0[tid] = hist[tid];
    __syncthreads();
    for (int st = 1; st < 256; st <<= 1) {
      unsigned mine = scan0[tid];
      unsigned oth = (tid + st < 256) ? scan0[tid + st] : 0u;
      __syncthreads();
      scan0[tid] = mine + oth;
      __syncthreads();
    }
    if (p == 0) {
      if (tid == 0) sh_ctot = scan0[0];
      __syncthreads();
      if (sh_ctot <= (unsigned)K) { smallcase = true; break; }
    }
    unsigned nxt = (tid == 255) ? 0u : scan0[tid + 1];
    if (scan0[tid] >= need && nxt < need) { sh_selbin = tid; sh_need = need - nxt; }
    __syncthreads();
    pfx = (pfx << 8) | sh_selbin;
    need = sh_need;
    __syncthreads();
  }
  unsigned pivot16 = smallcase ? 0x3D4Cu : pfx;

  if (tid == 0) sh_cnt = 0;
  __syncthreads();
  for (int a = tid; a < A; a += 256) {
    double sd = get_sd(conf, marr, sarr, base + a, c);
    if (sd >= TH_CONF) {
      float f = (float)sd;
      if ((__float_as_uint(f) >> 16) >= pivot16) {
        unsigned pos = atomicAdd(&sh_cnt, 1u);
        if (pos < 512) {
          unsigned long long db = (unsigned long long)__double_as_longlong(sd);
          cand[pos] = (db & 0xFFFFFFFFFFFF0000ull) |
                      (unsigned long long)(65535u - (unsigned)a);
        }
      }
    }
  }
  __syncthreads();
  unsigned ccount = sh_cnt < 512u ? sh_cnt : 512u;
  unsigned Ct = ccount < (unsigned)K ? ccount : (unsigned)K;
  for (int i = tid; i < 512; i += 256)
    if ((unsigned)i >= ccount) cand[i] = 0ull;
  __syncthreads();

  for (unsigned k2 = 2; k2 <= 512; k2 <<= 1) {
    for (unsigned j = k2 >> 1; j > 0; j >>= 1) {
      for (unsigned i = tid; i < 512; i += 256) {
        unsigned ixj = i ^ j;
        if (ixj > i) {
          unsigned long long va = cand[i], vb = cand[ixj];
          bool desc = ((i & k2) == 0);
          if (desc ? (va < vb) : (va > vb)) { cand[i] = vb; cand[ixj] = va; }
        }
      }
      __syncthreads();
    }
  }

  if ((unsigned)tid < Ct) {
    unsigned a = 65535u - (unsigned)(cand[tid] & 0xFFFFull);
    double o[4];
    decode_d(loc, anchor, base + a, a, o);
    cbd[tid * 4 + 0] = o[0]; cbd[tid * 4 + 1] = o[1];
    cbd[tid * 4 + 2] = o[2]; cbd[tid * 4 + 3] = o[3];
    ar[tid] = (o[2] - o[0]) * (o[3] - o[1]);
  }
  __syncthreads();

  for (int id = tid; id < (int)Ct * 8; id += 256) {
    int i = id >> 3, w = id & 7;
    double xi0 = cbd[i * 4 + 0], yi0 = cbd[i * 4 + 1];
    double xi1 = cbd[i * 4 + 2], yi1 = cbd[i * 4 + 3];
    double ai = ar[i];
    unsigned bits = 0;
    int j0 = w * 32;
    for (int jj = 0; jj < 32; ++jj) {
      int j = j0 + jj;
      if (j < (int)Ct) {
        double ltx = fmax(xi0, cbd[j * 4 + 0]);
        double lty = fmax(yi0, cbd[j * 4 + 1]);
        double rbx = fmin(xi1, cbd[j * 4 + 2]);
        double rby = fmin(yi1, cbd[j * 4 + 3]);
        double iw = fmax(rbx - ltx, 0.0);
        double ih = fmax(rby - lty, 0.0);
        double inter = iw * ih;
        double iou = inter / (ai + ar[j] - inter + 1e-9);
        if (iou > TH_IOU) bits |= (1u << jj);
      }
    }
    rows[i * 8 + w] = bits;
  }
  __syncthreads();

  if (tid < 64) {
    unsigned supp = 0;
    for (int i = 0; i < (int)Ct; ++i) {
      unsigned wsrc = __shfl(supp, i >> 5);
      bool kkeep = ((wsrc >> (i & 31)) & 1u) == 0u;
      if (tid == 0) kp[i] = kkeep ? 1u : 0u;
      unsigned rw = (tid < 8) ? rows[i * 8 + tid] : 0u;
      if (kkeep) supp |= rw;
    }
  }
  __syncthreads();

  if (tid < K) {
    bool kkeep = ((unsigned)tid < Ct) && (kp[tid] != 0u);
    float o0 = 0.f, o1 = 0.f, o2 = 0.f, o3 = 0.f, o4 = 0.f;
    if (kkeep) {
      o0 = (float)cbd[tid * 4 + 0]; o1 = (float)cbd[tid * 4 + 1];
      o2 = (float)cbd[tid * 4 + 2]; o3 = (float)cbd[tid * 4 + 3];
      double sd = __longlong_as_double(
          (long long)(cand[tid] & 0xFFFFFFFFFFFF0000ull));
      o4 = (float)sd;
    }
    size_t ob = ((size_t)bc * K + tid) * 5;
    out[ob + 0] = o0; out[ob + 1] = o1; out[ob + 2] = o2;
    out[ob + 3] = o3; out[ob + 4] = o4;
    out[(size_t)B * NC * K * 5 + (size_t)bc * K + tid] = kkeep ? 1.f : 0.f;
  }
}

extern "C" void kernel_launch(void* const* d_in, const int* in_sizes, int n_in,
                              void* d_out, int out_size, void* d_ws, size_t ws_size,
                              hipStream_t stream) {
  (void)in_sizes; (void)n_in; (void)out_size;
  const float* conf = (const float*)d_in[0];
  const float* loc = (const float*)d_in[1];
  const float* anchor = (const float*)d_in[2];
  float* out = (float*)d_out;

  size_t nBA = (size_t)B * A;
  size_t off_sarr = 0;
  size_t off_marr = off_sarr + nBA * sizeof(double);
  size_t off_keys = off_marr + nBA * sizeof(float);
  size_t need_fast = off_keys + nBA * NC * sizeof(unsigned char);  // ~32.5 MB
  size_t need_mid = nBA * (sizeof(float) + sizeof(double));        // 12 MB

  if (ws_size >= need_fast) {
    double* sarr = (double*)((char*)d_ws + off_sarr);
    float* marr = (float*)((char*)d_ws + off_marr);
    unsigned char* keys = (unsigned char*)((char*)d_ws + off_keys);
    prep_fast<<<(B * A) / 256, 256, 0, stream>>>(conf, marr, sarr, keys);
    select2_kernel<<<B * NC, 512, 0, stream>>>(conf, marr, sarr, loc, anchor,
                                               keys, out);
  } else if (ws_size >= need_mid) {
    float* marr = (float*)d_ws;
    double* sarr = (double*)((char*)d_ws + nBA * sizeof(float));
    prep_kernel<<<(B * A) / 256, 256, 0, stream>>>(conf, marr, sarr);
    select_nms_kernel<<<B * NC, 256, 0, stream>>>(conf, marr, sarr, loc, anchor, out);
  } else {
    select_nms_kernel<<<B * NC, 256, 0, stream>>>(conf, nullptr, nullptr, loc, anchor, out);
  }
}